// Round 5
// baseline (439.442 us; speedup 1.0000x reference)
//
#include <hip/hip_runtime.h>
#include <stdint.h>

#define BATCH 4
#define N1 25200
#define NROW 50400           // N1 + N2
#define NCLS 100
#define TOT (BATCH*NROW)     // 201600
#define CAPB 1280            // per-(batch,class) bucket capacity (mean ~929, +11 sigma)
#define LMAX 2048            // pow2 >= CAPB for bitonic
#define SCORE_T 0.25f
#define IOU_T 0.45f
#define MAXWH 7680.0f

#define X1_SLAB 64
#define X1_SPB 394           // ceil(25200/64)
#define X2_SLAB 256
#define X2_SPB 99            // ceil(25200/256)

typedef unsigned long long u64;

// ---------------- Kernel A: decode + argmax + direct bucket scatter (fused)
// Stages row slabs to LDS via float4 (coalesced), computes box + class argmax,
// and scatters the packed key (score_bits<<32)|~n straight into its bucket.
__global__ __launch_bounds__(256) void k_rows(const float* __restrict__ x1,
                                              const float* __restrict__ x2,
                                              float4* __restrict__ boxes4,
                                              u64* __restrict__ csrKey,
                                              int* __restrict__ fill) {
    __shared__ float4 ld4[1600];          // 25.6 KB (>= 64*85 and 256*25 floats)
    float* ld = (float*)ld4;
    int blk = blockIdx.x;
    int t = threadIdx.x;
    const int NX1 = BATCH * X1_SPB;
    if (blk < NX1) {
        int b = blk / X1_SPB, s = blk - b * X1_SPB;
        int r0 = s * X1_SLAB;
        int nr = min(X1_SLAB, N1 - r0);
        const float4* src = (const float4*)(x1 + ((size_t)b * N1 + r0) * 85);
        int count4 = (nr * 85) >> 2;      // nr in {64,48} -> divisible by 4
        for (int i = t; i < count4; i += 256) ld4[i] = src[i];
        __syncthreads();
        int row = t >> 2, sub = t & 3;
        if (row < nr) {
            const float* p = ld + row * 85;
            float conf = p[4];
            // per-quad argmax, packed key (score_bits<<32)|~j => (score desc, first j)
            u64 key = 0ULL;
            int base = sub * 20;
            for (int c = 0; c < 20; ++c) {
                int j = base + c;
                float v = p[5 + j] * conf;
                u64 kk = ((u64)__float_as_uint(v) << 32) | (unsigned)~(unsigned)j;
                if (kk > key) key = kk;
            }
            u64 o;
            o = __shfl_xor(key, 1, 64); if (o > key) key = o;
            o = __shfl_xor(key, 2, 64); if (o > key) key = o;
            if (sub == 0) {
                float best = __uint_as_float((unsigned)(key >> 32));
                int bestj = ~(unsigned)key;
                if (best >= SCORE_T) {
                    int n = r0 + row;                 // row index within batch
                    int r = b * NROW + n;
                    float cx = p[0], cy = p[1], w = p[2], h = p[3];
                    boxes4[r] = make_float4(cx - 0.5f * w, cy - 0.5f * h,
                                            cx + 0.5f * w, cy + 0.5f * h);
                    int bucket = b * NCLS + bestj;
                    int pos = atomicAdd(&fill[bucket], 1);
                    u64 k2 = ((u64)__float_as_uint(best) << 32) | (unsigned)~(unsigned)n;
                    if (pos < CAPB) csrKey[(size_t)bucket * CAPB + pos] = k2;
                }
            }
        }
    } else {
        int blk2 = blk - NX1;
        int b = blk2 / X2_SPB, s = blk2 - b * X2_SPB;
        int r0 = s * X2_SLAB;
        int nr = min(X2_SLAB, N1 - r0);
        const float4* src = (const float4*)(x2 + ((size_t)b * N1 + r0) * 25);
        int count4 = (nr * 25) >> 2;      // nr in {256,112} -> divisible by 4
        for (int i = t; i < count4; i += 256) ld4[i] = src[i];
        __syncthreads();
        if (t < nr) {
            const float* p = ld + t * 25;
            float conf = p[4];
            // classes 0..79 are exact zeros in the padded vector
            float best = 0.0f; int bestj = 0;
            for (int j2 = 0; j2 < 20; ++j2) {
                float v = p[5 + j2] * conf;
                if (v > best) { best = v; bestj = 80 + j2; }
            }
            if (best >= SCORE_T) {
                int n = N1 + r0 + t;
                int r = b * NROW + n;
                float cx = p[0], cy = p[1], w = p[2], h = p[3];
                boxes4[r] = make_float4(cx - 0.5f * w, cy - 0.5f * h,
                                        cx + 0.5f * w, cy + 0.5f * h);
                int bucket = b * NCLS + bestj;
                int pos = atomicAdd(&fill[bucket], 1);
                u64 k2 = ((u64)__float_as_uint(best) << 32) | (unsigned)~(unsigned)n;
                if (pos < CAPB) csrKey[(size_t)bucket * CAPB + pos] = k2;
            }
        }
    }
}

// ---------------- Kernel C: per-bucket sort (256 thr) + single-wave greedy NMS
// Greedy phase: wave 0 only, alive-mask in registers, per-slot ballot argmin.
// Zero barriers, zero cross-wave traffic in the serial loop.
__global__ __launch_bounds__(256) void k_nms(const float4* __restrict__ boxes4,
                                             const u64* __restrict__ csrKey,
                                             const int* __restrict__ fillArr,
                                             u64* __restrict__ accKey,
                                             int* __restrict__ accCnt) {
    __shared__ u64 sk[LMAX];        // 16 KB
    __shared__ float4 cQ[CAPB];     // 20 KB, quantized nms-boxes (AoS float4)
    int bucket = blockIdx.x;
    int b = bucket / NCLS, c = bucket - b * NCLS;
    int cnt0 = min(fillArr[bucket], CAPB);
    if (cnt0 == 0) return;          // accCnt pre-zeroed by memset
    int t = threadIdx.x;
    int L = 1; while (L < cnt0) L <<= 1;
    for (int i = t; i < L; i += 256)
        sk[i] = (i < cnt0) ? csrKey[(size_t)bucket * CAPB + i] : 0ULL;
    __syncthreads();
    // bitonic sort, descending (keys unique -> deterministic)
    for (int k = 2; k <= L; k <<= 1) {
        for (int j = k >> 1; j > 0; j >>= 1) {
            for (int i = t; i < L; i += 256) {
                int pp = i ^ j;
                if (pp > i) {
                    bool dir = ((i & k) == 0);
                    u64 a = sk[i], bb = sk[pp];
                    bool sw = dir ? (a < bb) : (a > bb);
                    if (sw) { sk[i] = bb; sk[pp] = a; }
                }
            }
            __syncthreads();
        }
    }
    // stage quantized boxes: fl(box + class*7680) exactly as the reference
    float off = (float)c * MAXWH;
    for (int i = t; i < cnt0; i += 256) {
        int n = ~(unsigned)sk[i];
        float4 v = boxes4[b * NROW + n];
        v.x += off; v.y += off; v.z += off; v.w += off;
        cQ[i] = v;
    }
    __syncthreads();
    if (t >= 64) return;            // greedy: wave 0 only, no barriers from here
    int lane = t;
    int SLOTS = (cnt0 + 63) >> 6;   // <= 20
    unsigned alive = 0;
    for (int s = 0; s < SLOTS; ++s)
        if (lane + (s << 6) < cnt0) alive |= 1u << s;
    int cur = 0, m = 0, sMin = 0;
    while (true) {
        if (lane == 0) accKey[(size_t)bucket * 100 + m] = sk[cur];
        ++m;
        if (m == 100) break;
        float4 q = cQ[cur];                       // lane-uniform LDS broadcast
        float qa = (q.z - q.x) * (q.w - q.y);
        int next = -1;
        for (int s = sMin; s < SLOTS; ++s) {      // fused suppress + first-alive scan
            bool al = (alive >> s) & 1;
            if (al) {
                int j = (s << 6) + lane;
                float4 a = cQ[j];
                float xx1 = fmaxf(a.x, q.x), yy1 = fmaxf(a.y, q.y);
                float xx2 = fminf(a.z, q.z), yy2 = fminf(a.w, q.w);
                float inter = fmaxf(xx2 - xx1, 0.0f) * fmaxf(yy2 - yy1, 0.0f);
                float ab = (a.z - a.x) * (a.w - a.y);
                float iou = inter / (qa + ab - inter + 1e-9f);  // exact IEEE div
                if (iou > IOU_T || j == cur) { alive &= ~(1u << s); al = false; }
            }
            if (next < 0) {                       // uniform: stop balloting once found
                u64 bb = __ballot(al);
                if (bb == 0ULL) sMin = s + 1;     // slot drained for good (monotone)
                else next = (s << 6) + __builtin_ctzll(bb);
            }
        }
        if (next < 0) break;
        cur = next;
    }
    if (lane == 0) accCnt[bucket] = m;
}

// ---------------- Kernel D: per-batch merge, single-wave shuffle tournament
__global__ __launch_bounds__(256) void k_merge(const float4* __restrict__ boxes4,
                                               const u64* __restrict__ accKey,
                                               const int* __restrict__ accCnt,
                                               float* __restrict__ out) {
    __shared__ u64 keys[NCLS * 100];   // 80 KB
    __shared__ u64 winKey[100];
    __shared__ int winCls[100];
    __shared__ int cnts[NCLS];
    int b = blockIdx.x;
    int t = threadIdx.x;
    if (t < NCLS) cnts[t] = accCnt[b * NCLS + t];
    __syncthreads();
    for (int i = t; i < NCLS * 100; i += 256) {
        int c = i / 100, j = i - c * 100;
        keys[i] = (j < cnts[c]) ? accKey[(size_t)(b * NCLS + c) * 100 + j] : 0ULL;
    }
    __syncthreads();
    if (t < 64) {
        int c0 = 2 * t, c1 = 2 * t + 1;     // lanes 50..63 own no real class
        int h0 = 0, h1 = 0;
        u64 hk0 = 0ULL, hk1 = 0ULL;
        if (c0 < NCLS && cnts[c0] > 0) hk0 = keys[c0 * 100];
        if (c1 < NCLS && cnts[c1] > 0) hk1 = keys[c1 * 100];
        for (int step = 0; step < 100; ++step) {
            u64 k; int cls;
            if (hk0 >= hk1) { k = hk0; cls = c0; } else { k = hk1; cls = c1; }
            for (int o = 1; o < 64; o <<= 1) {
                u64 ok = __shfl_xor(k, o, 64);
                int oc = __shfl_xor(cls, o, 64);
                if (ok > k) { k = ok; cls = oc; }
            }
            if (t == 0) { winKey[step] = k; winCls[step] = cls; }
            if (k != 0ULL) {                // winner is a real class (<NCLS) here
                if (cls == c0)      { ++h0; hk0 = (h0 < cnts[c0]) ? keys[c0 * 100 + h0] : 0ULL; }
                else if (cls == c1) { ++h1; hk1 = (h1 < cnts[c1]) ? keys[c1 * 100 + h1] : 0ULL; }
            }
        }
    }
    __syncthreads();
    if (t < 100) {                          // parallel output gather
        u64 k = winKey[t];
        unsigned n = ~(unsigned)k;
        float* o7 = out + (size_t)(b * 100 + t) * 7;
        if (k == 0ULL || n >= (unsigned)NROW) {
            o7[0] = -1.0f;
            o7[1] = 0.0f; o7[2] = 0.0f; o7[3] = 0.0f;
            o7[4] = 0.0f; o7[5] = 0.0f; o7[6] = 0.0f;
        } else {
            float4 bx = boxes4[b * NROW + (int)n];
            o7[0] = (float)b;
            o7[1] = bx.x; o7[2] = bx.y; o7[3] = bx.z; o7[4] = bx.w;
            o7[5] = (float)winCls[t];
            o7[6] = __uint_as_float((unsigned)(k >> 32));
        }
    }
}

extern "C" void kernel_launch(void* const* d_in, const int* in_sizes, int n_in,
                              void* d_out, int out_size, void* d_ws, size_t ws_size,
                              hipStream_t stream) {
    const float* x1 = (const float*)d_in[0];
    const float* x2 = (const float*)d_in[1];
    float* out = (float*)d_out;

    // workspace layout (~7.3 MiB)
    float4* boxes4 = (float4*)d_ws;                          // TOT float4
    u64* csrKey = (u64*)(boxes4 + TOT);                      // 400*CAPB u64
    u64* accKey = csrKey + (size_t)BATCH * NCLS * CAPB;      // 400*100 u64
    int* fill   = (int*)(accKey + (size_t)BATCH * NCLS * 100);  // 400
    int* accCnt = fill + BATCH * NCLS;                       // 400 (contiguous w/ fill)

    hipMemsetAsync(fill, 0, sizeof(int) * 2 * BATCH * NCLS, stream);

    int rowBlocks = BATCH * X1_SPB + BATCH * X2_SPB;         // 1576 + 396 = 1972
    k_rows<<<rowBlocks, 256, 0, stream>>>(x1, x2, boxes4, csrKey, fill);
    k_nms<<<BATCH * NCLS, 256, 0, stream>>>(boxes4, csrKey, fill, accKey, accCnt);
    k_merge<<<BATCH, 256, 0, stream>>>(boxes4, accKey, accCnt, out);
}

// Round 6
// 191.244 us; speedup vs baseline: 2.2978x; 2.2978x over previous
//
#include <hip/hip_runtime.h>
#include <stdint.h>

#pragma clang fp contract(off)   // pin IEEE single-rounding: must match numpy ref bit-exactly

#define BATCH 4
#define N1 25200
#define NROW 50400           // N1 + N2
#define NCLS 100
#define TOT (BATCH*NROW)     // 201600
#define CAPB 2048            // per-(batch,class) capacity (expected max ~950)
#define SCORE_T 0.25f
#define IOU_T 0.45f
#define MAXWH 7680.0f

#define X1_SLAB 64
#define X1_SPB 394           // ceil(25200/64)
#define X2_SLAB 256
#define X2_SPB 99            // ceil(25200/256)

typedef unsigned long long u64;

// key = score_bits(63..32) | (n^0xFFFF)(23..8) | catid(7..0)
// descending key order == (score desc, n asc); catid below n never decides
// ((score,n) unique per row). Within a bucket catid is constant.
__device__ __forceinline__ u64 pack_key(unsigned sb, int n, int cid) {
    return ((u64)sb << 32) | ((u64)(unsigned)((n ^ 0xFFFF) & 0xFFFF) << 8) | (u64)(unsigned)cid;
}

// ---------------- Kernel A: decode + argmax -> boxes4 + one packed key per row.
// No atomics, no scatter. rowKey[r]=0 iff score < SCORE_T.
__global__ __launch_bounds__(256) void k_rows(const float* __restrict__ x1,
                                              const float* __restrict__ x2,
                                              float4* __restrict__ boxes4,
                                              u64* __restrict__ rowKey) {
    __shared__ float4 ld4[1600];          // 25.6 KB (>= 64*85 and 256*25 floats)
    float* ld = (float*)ld4;
    int blk = blockIdx.x;
    int t = threadIdx.x;
    const int NX1 = BATCH * X1_SPB;
    if (blk < NX1) {
        int b = blk / X1_SPB, s = blk - b * X1_SPB;
        int r0 = s * X1_SLAB;
        int nr = min(X1_SLAB, N1 - r0);
        const float4* src = (const float4*)(x1 + ((size_t)b * N1 + r0) * 85);
        int count4 = (nr * 85) >> 2;      // nr in {64,48} -> divisible by 4
        for (int i = t; i < count4; i += 256) ld4[i] = src[i];
        __syncthreads();
        int row = t >> 2, sub = t & 3;
        if (row < nr) {
            const float* p = ld + row * 85;
            float conf = p[4];
            // per-quad argmax; packed (score_bits<<32)|~j => (score desc, first j)
            u64 key = 0ULL;
            int base = sub * 20;
            for (int c = 0; c < 20; ++c) {
                int j = base + c;
                float v = p[5 + j] * conf;
                u64 kk = ((u64)__float_as_uint(v) << 32) | (unsigned)~(unsigned)j;
                if (kk > key) key = kk;
            }
            u64 o;
            o = __shfl_xor(key, 1, 64); if (o > key) key = o;
            o = __shfl_xor(key, 2, 64); if (o > key) key = o;
            if (sub == 0) {
                float best = __uint_as_float((unsigned)(key >> 32));
                int bestj = ~(unsigned)key;
                int n = r0 + row;
                int r = b * NROW + n;
                u64 outk = 0ULL;
                if (best >= SCORE_T) {
                    float cx = p[0], cy = p[1], w = p[2], h = p[3];
                    boxes4[r] = make_float4(cx - 0.5f * w, cy - 0.5f * h,
                                            cx + 0.5f * w, cy + 0.5f * h);
                    outk = pack_key((unsigned)(key >> 32), n, bestj);
                }
                rowKey[r] = outk;         // every row written (no stale poison)
            }
        }
    } else {
        int blk2 = blk - NX1;
        int b = blk2 / X2_SPB, s = blk2 - b * X2_SPB;
        int r0 = s * X2_SLAB;
        int nr = min(X2_SLAB, N1 - r0);
        const float4* src = (const float4*)(x2 + ((size_t)b * N1 + r0) * 25);
        int count4 = (nr * 25) >> 2;      // nr in {256,112} -> divisible by 4
        for (int i = t; i < count4; i += 256) ld4[i] = src[i];
        __syncthreads();
        if (t < nr) {
            const float* p = ld + t * 25;
            float conf = p[4];
            // padded classes 0..79 are exact zeros; can't pass threshold
            float best = 0.0f; int bestj = 0;
            for (int j2 = 0; j2 < 20; ++j2) {
                float v = p[5 + j2] * conf;
                if (v > best) { best = v; bestj = 80 + j2; }
            }
            int n = N1 + r0 + t;
            int r = b * NROW + n;
            u64 outk = 0ULL;
            if (best >= SCORE_T) {
                float cx = p[0], cy = p[1], w = p[2], h = p[3];
                boxes4[r] = make_float4(cx - 0.5f * w, cy - 0.5f * h,
                                        cx + 0.5f * w, cy + 0.5f * h);
                outk = pack_key(__float_as_uint(best), n, bestj);
            }
            rowKey[r] = outk;
        }
    }
}

// ---------------- Kernel C: per-bucket compact (scan rowKey) + sort + chunked
// wave-greedy NMS. Serial chain = per-ACCEPT (<=100), each ~70cy of shuffles.
__global__ __launch_bounds__(256) void k_nms(const float4* __restrict__ boxes4,
                                             const u64* __restrict__ rowKey,
                                             u64* __restrict__ accKey,
                                             int* __restrict__ accCnt) {
    __shared__ u64 sk[CAPB];              // 16 KB
    __shared__ float cQ0[CAPB], cQ1[CAPB], cQ2[CAPB], cQ3[CAPB];  // 32 KB SoA
    __shared__ float accQ[100 * 4];
    __shared__ float accA[100];
    __shared__ int lcnt;
    int bucket = blockIdx.x;
    int b = bucket / NCLS, c = bucket - b * NCLS;
    int t = threadIdx.x;
    if (t == 0) lcnt = 0;
    __syncthreads();
    // ---- compaction: scan the batch's key array (coalesced 16B loads)
    const ulonglong2* rk2 = (const ulonglong2*)(rowKey + (size_t)b * NROW);
    for (int i = t; i < NROW / 2; i += 256) {
        ulonglong2 kk = rk2[i];
        bool m0 = (kk.x != 0ULL) && ((int)(kk.x & 0xFF) == c);
        bool m1 = (kk.y != 0ULL) && ((int)(kk.y & 0xFF) == c);
        u64 mb0 = __ballot(m0);
        u64 mb1 = __ballot(m1);
        if ((mb0 | mb1) != 0ULL) {
            int lane = t & 63;
            int basew;
            if (lane == 0) basew = atomicAdd(&lcnt, __popcll(mb0) + __popcll(mb1));
            basew = __shfl(basew, 0, 64);
            u64 below = (1ULL << lane) - 1ULL;
            if (m0) {
                int pos = basew + __popcll(mb0 & below);
                if (pos < CAPB) sk[pos] = kk.x;
            }
            if (m1) {
                int pos = basew + __popcll(mb0) + __popcll(mb1 & below);
                if (pos < CAPB) sk[pos] = kk.y;
            }
        }
    }
    __syncthreads();
    int cnt0 = min(lcnt, CAPB);
    if (cnt0 == 0) { if (t == 0) accCnt[bucket] = 0; return; }
    // ---- pad + bitonic sort (descending; keys unique, 0 = -inf sentinel)
    int L = 1; while (L < cnt0) L <<= 1;
    for (int i = cnt0 + t; i < L; i += 256) sk[i] = 0ULL;
    __syncthreads();
    for (int k = 2; k <= L; k <<= 1) {
        for (int j = k >> 1; j > 0; j >>= 1) {
            for (int i = t; i < L; i += 256) {
                int pp = i ^ j;
                if (pp > i) {
                    bool dir = ((i & k) == 0);
                    u64 a = sk[i], bb = sk[pp];
                    bool sw = dir ? (a < bb) : (a > bb);
                    if (sw) { sk[i] = bb; sk[pp] = a; }
                }
            }
            __syncthreads();
        }
    }
    // ---- stage quantized nms-boxes: fl(box + c*7680) exactly as the reference
    float off = (float)c * MAXWH;
    for (int i = t; i < cnt0; i += 256) {
        u64 k = sk[i];
        int n = 0xFFFF ^ (int)((k >> 8) & 0xFFFF);
        float4 v = boxes4[b * NROW + n];
        cQ0[i] = v.x + off; cQ1[i] = v.y + off;
        cQ2[i] = v.z + off; cQ3[i] = v.w + off;
    }
    __syncthreads();
    if (t >= 64) return;                  // greedy on wave 0 only, no barriers
    int lane = t;
    int m = 0;
    for (int base = 0; base < cnt0 && m < 100; base += 64) {
        int j = base + lane;
        bool alive = (j < cnt0);
        float ax = 0.f, ay = 0.f, az = 0.f, aw = 0.f, aArea = 0.f;
        u64 myKey = 0ULL;
        if (alive) {
            ax = cQ0[j]; ay = cQ1[j]; az = cQ2[j]; aw = cQ3[j];
            myKey = sk[j];
            aArea = (az - ax) * (aw - ay);
        }
        // suppress vs previously-accepted (LDS broadcast reads, uniform loop)
        for (int k2 = 0; k2 < m; ++k2) {
            if (__ballot(alive) == 0ULL) break;          // uniform early-out
            float qx = accQ[k2 * 4 + 0], qy = accQ[k2 * 4 + 1];
            float qz = accQ[k2 * 4 + 2], qw = accQ[k2 * 4 + 3];
            float xx1 = fmaxf(ax, qx), yy1 = fmaxf(ay, qy);
            float xx2 = fminf(az, qz), yy2 = fminf(aw, qw);
            float inter = fmaxf(xx2 - xx1, 0.0f) * fmaxf(yy2 - yy1, 0.0f);
            float d = accA[k2] + aArea - inter + 1e-9f;  // fl((a+b)-inter)+eps
            if (inter / d > IOU_T) alive = false;
        }
        // intra-chunk resolution: accept first alive, suppress within chunk
        u64 av = __ballot(alive);
        while (av != 0ULL && m < 100) {
            int f = __builtin_ctzll(av);
            float qx = __shfl(ax, f, 64), qy = __shfl(ay, f, 64);
            float qz = __shfl(az, f, 64), qw = __shfl(aw, f, 64);
            float qa = __shfl(aArea, f, 64);
            if (lane == f) {
                accQ[m * 4 + 0] = ax; accQ[m * 4 + 1] = ay;
                accQ[m * 4 + 2] = az; accQ[m * 4 + 3] = aw;
                accA[m] = aArea;
                accKey[(size_t)bucket * 100 + m] = myKey;
                alive = false;
            }
            ++m;
            if (alive) {                  // all remaining alive lanes are > f
                float xx1 = fmaxf(ax, qx), yy1 = fmaxf(ay, qy);
                float xx2 = fminf(az, qz), yy2 = fminf(aw, qw);
                float inter = fmaxf(xx2 - xx1, 0.0f) * fmaxf(yy2 - yy1, 0.0f);
                float d = qa + aArea - inter + 1e-9f;
                if (inter / d > IOU_T) alive = false;
            }
            av = __ballot(alive);
        }
    }
    if (lane == 0) accCnt[bucket] = m;
}

// ---------------- Kernel D: per-batch merge, single-wave shuffle tournament
__global__ __launch_bounds__(256) void k_merge(const float4* __restrict__ boxes4,
                                               const u64* __restrict__ accKey,
                                               const int* __restrict__ accCnt,
                                               float* __restrict__ out) {
    __shared__ u64 keys[NCLS * 100];      // 80 KB
    __shared__ u64 winKey[100];
    __shared__ int cnts[NCLS];
    int b = blockIdx.x;
    int t = threadIdx.x;
    if (t < NCLS) cnts[t] = accCnt[b * NCLS + t];
    __syncthreads();
    for (int i = t; i < NCLS * 100; i += 256) {
        int c = i / 100, j = i - c * 100;
        keys[i] = (j < cnts[c]) ? accKey[(size_t)(b * NCLS + c) * 100 + j] : 0ULL;
    }
    __syncthreads();
    if (t < 64) {
        int c0 = 2 * t, c1 = 2 * t + 1;   // lanes 50..63 own no real class
        int h0 = 0, h1 = 0;
        u64 hk0 = (c0 < NCLS && cnts[c0] > 0) ? keys[c0 * 100] : 0ULL;  // OOB guards
        u64 hk1 = (c1 < NCLS && cnts[c1] > 0) ? keys[c1 * 100] : 0ULL;
        for (int step = 0; step < 100; ++step) {
            u64 k = (hk0 >= hk1) ? hk0 : hk1;
            for (int o = 1; o < 64; o <<= 1) {
                u64 ok = __shfl_xor(k, o, 64);
                if (ok > k) k = ok;
            }
            if (t == 0) winKey[step] = k;
            if (k != 0ULL) {              // winner's class is in its key
                int cls = (int)(k & 0xFF);
                if (cls == c0)      { ++h0; hk0 = (h0 < cnts[c0]) ? keys[c0 * 100 + h0] : 0ULL; }
                else if (cls == c1) { ++h1; hk1 = (h1 < cnts[c1]) ? keys[c1 * 100 + h1] : 0ULL; }
            }
        }
    }
    __syncthreads();
    if (t < 100) {                        // parallel output gather
        u64 k = winKey[t];
        float* o7 = out + (size_t)(b * 100 + t) * 7;
        if (k == 0ULL) {
            o7[0] = -1.0f;
            o7[1] = 0.0f; o7[2] = 0.0f; o7[3] = 0.0f;
            o7[4] = 0.0f; o7[5] = 0.0f; o7[6] = 0.0f;
        } else {
            int n = 0xFFFF ^ (int)((k >> 8) & 0xFFFF);
            int cid = (int)(k & 0xFF);
            float4 bx = boxes4[b * NROW + n];
            o7[0] = (float)b;
            o7[1] = bx.x; o7[2] = bx.y; o7[3] = bx.z; o7[4] = bx.w;
            o7[5] = (float)cid;
            o7[6] = __uint_as_float((unsigned)(k >> 32));
        }
    }
}

extern "C" void kernel_launch(void* const* d_in, const int* in_sizes, int n_in,
                              void* d_out, int out_size, void* d_ws, size_t ws_size,
                              hipStream_t stream) {
    const float* x1 = (const float*)d_in[0];
    const float* x2 = (const float*)d_in[1];
    float* out = (float*)d_out;

    // workspace (~5.2 MiB): boxes4 | rowKey | accKey | accCnt
    float4* boxes4 = (float4*)d_ws;                          // TOT float4
    u64* rowKey = (u64*)(boxes4 + TOT);                      // TOT u64
    u64* accKey = rowKey + TOT;                              // 400*100 u64
    int* accCnt = (int*)(accKey + (size_t)BATCH * NCLS * 100);  // 400 (always written)

    int rowBlocks = BATCH * X1_SPB + BATCH * X2_SPB;         // 1576 + 396 = 1972
    k_rows<<<rowBlocks, 256, 0, stream>>>(x1, x2, boxes4, rowKey);
    k_nms<<<BATCH * NCLS, 256, 0, stream>>>(boxes4, rowKey, accKey, accCnt);
    k_merge<<<BATCH, 256, 0, stream>>>(boxes4, accKey, accCnt, out);
}